// Round 5
// baseline (866.894 us; speedup 1.0000x reference)
//
#include <hip/hip_runtime.h>
#include <stdint.h>

#define N_NODES 50000
#define N_EDGES 400000
#define M_PAD   50176   // 196 * 256

typedef __attribute__((ext_vector_type(8))) __bf16 bf16x8;
typedef __attribute__((ext_vector_type(4))) float floatx4;

__device__ __forceinline__ unsigned short f2bf(float f) {
    unsigned int u = __float_as_uint(f);
    unsigned int r = (u + 0x7fffu + ((u >> 16) & 1u)) >> 16;
    return (unsigned short)r;
}

__device__ __forceinline__ void gload_lds16(const void* g, void* l) {
    __builtin_amdgcn_global_load_lds((__attribute__((address_space(1))) void*)g,
                                     (__attribute__((address_space(3))) void*)l,
                                     16, 0, 0);
}

// ---------------- x fp32 -> bf16 (padded to M_PAD rows) ----------------
__global__ void k_conv_x(const float* __restrict__ x, unsigned short* __restrict__ xb) {
    const int total = M_PAD * 256;  // float4 units per row
    for (int u = blockIdx.x * blockDim.x + threadIdx.x; u < total; u += gridDim.x * blockDim.x) {
        int row = u >> 8;
        int c4  = u & 255;
        float4 v = make_float4(0.f, 0.f, 0.f, 0.f);
        if (row < N_NODES) v = ((const float4*)x)[(size_t)row * 256 + c4];
        ushort4 o;
        o.x = f2bf(v.x); o.y = f2bf(v.y); o.z = f2bf(v.z); o.w = f2bf(v.w);
        ((ushort4*)xb)[u] = o;
    }
}

// ---------------- build W^T (bf16, [ncol=1024][k=1024]) + bias concat ----------------
__global__ void k_build_w(const float* __restrict__ Wq, const float* __restrict__ Wk,
                          const float* __restrict__ Wv, const float* __restrict__ Ws,
                          const float* __restrict__ bq, const float* __restrict__ bk,
                          const float* __restrict__ bv, const float* __restrict__ bs,
                          unsigned short* __restrict__ WT, float* __restrict__ biascat) {
    int idx = blockIdx.x * blockDim.x + threadIdx.x;
    if (idx < 1024 * 1024) {
        int n = idx >> 10;        // output col 0..1023
        int k = idx & 1023;       // input dim
        int g = n >> 8, d = n & 255;
        const float* W = (g == 0) ? Wq : (g == 1) ? Wk : (g == 2) ? Wv : Ws;
        WT[idx] = f2bf(W[k * 256 + d]);
    }
    if (idx < 1024) {
        int g = idx >> 8, d = idx & 255;
        const float* B = (g == 0) ? bq : (g == 1) ? bk : (g == 2) ? bv : bs;
        biascat[idx] = B[d];
    }
}

// ---------------- bf16 MFMA GEMM: C[M_PAD][1024] = A[M_PAD][1024] * B[1024][1024] + bias ----
// 256x256 tile, BK=32, 512 threads = 8 waves (2M x 4N; each wave owns 128x64 of C).
// A: LDS, 4-deep buffered (4 x 16KB), staged 2 K-tiles ahead via global_load_lds with
//    XOR-swizzled granules (swizzle applied on the GLOBAL source; LDS writes stay linear).
// B: global->VGPR direct (L2-resident 2MB panel), register double-buffered (2x unroll).
// Tile boundary: counted s_waitcnt vmcnt(6) (A(kt+1) landed; B(kt+1)+A(kt+2) in flight),
// then one barrier. vmcnt never drains to 0 in the main loop (T4).
__launch_bounds__(512, 2)
__global__ void k_gemm(const unsigned short* __restrict__ A,
                       const unsigned short* __restrict__ BT,
                       const float* __restrict__ bias,
                       float* __restrict__ Cmat) {
    __shared__ unsigned short As[4 * 8192];   // 4 bufs x 256rows x 32k bf16 = 64 KB

    // ---- bijective XCD-chunked swizzle: 784 = 8 XCD * 98; strips stay on one XCD ----
    const int wg  = blockIdx.x;               // 0..783
    const int idx = (wg & 7) * 98 + (wg >> 3);
    const int yt  = idx >> 2;                 // 0..195
    const int xt  = idx & 3;                  // 0..3
    const int row0 = yt * 256;
    const int col0 = xt * 256;

    const int t = threadIdx.x;
    const int w = t >> 6;                     // wave 0..7
    const int l = t & 63;
    const int lane15 = l & 15;
    const int quad   = l >> 4;

    const int wr = (w >> 2) * 128;            // wave M-offset (2 M-waves)
    const int wc = (w & 3) * 64;              // wave N-offset (4 N-waves)

    // swizzle constants (granule q ^= (row>>1)&3; both reduce to lane-only forms)
    const int qx   = quad ^ ((lane15 >> 1) & 3);      // read-side
    const int qsrc = (l & 3) ^ ((l >> 3) & 3);        // stage-side (global source)
    const int srow = w * 16 + (l >> 2);               // stage row within half (h*128 + srow)

    unsigned short* Asl = As;

    floatx4 acc[8][4];
#pragma unroll
    for (int i = 0; i < 8; i++)
#pragma unroll
        for (int c = 0; c < 4; c++) acc[i][c] = (floatx4)0.f;

#define ASTAGE(buf, ktn)                                                                  \
    {                                                                                     \
        const size_t kko = (size_t)(ktn) * 32;                                            \
        _Pragma("unroll")                                                                 \
        for (int h = 0; h < 2; h++) {                                                     \
            int rowg = h * 128 + srow;                                                    \
            gload_lds16(A + (size_t)(row0 + rowg) * 1024 + kko + qsrc * 8,                \
                        Asl + (size_t)(buf) * 8192 + (h * 512 + w * 64) * 8);             \
        }                                                                                 \
    }

#define BPREF(BARR, ktn)                                                                  \
    {                                                                                     \
        const size_t kko = (size_t)(ktn) * 32;                                            \
        _Pragma("unroll")                                                                 \
        for (int c = 0; c < 4; c++)                                                       \
            BARR[c] = *(const bf16x8*)(BT + (size_t)(col0 + wc + c * 16 + lane15) * 1024  \
                                          + kko + quad * 8);                              \
    }

#define TILE(kt, BCUR, BNXT)                                                              \
    {                                                                                     \
        if ((kt) + 1 < 32) BPREF(BNXT, (kt) + 1);                                         \
        if ((kt) + 2 < 32) ASTAGE(((kt) + 2) & 3, (kt) + 2);                              \
        const unsigned short* Ab = Asl + (size_t)((kt) & 3) * 8192;                       \
        bf16x8 af[8];                                                                     \
        _Pragma("unroll")                                                                 \
        for (int i = 0; i < 8; i++)                                                       \
            af[i] = *(const bf16x8*)(Ab + (wr + i * 16 + lane15) * 32 + qx * 8);          \
        __builtin_amdgcn_s_setprio(1);                                                    \
        _Pragma("unroll")                                                                 \
        for (int i = 0; i < 8; i++)                                                       \
            _Pragma("unroll")                                                             \
            for (int c = 0; c < 4; c++)                                                   \
                acc[i][c] = __builtin_amdgcn_mfma_f32_16x16x32_bf16(af[i], BCUR[c],       \
                                                                   acc[i][c], 0, 0, 0);  \
        __builtin_amdgcn_s_setprio(0);                                                    \
        if ((kt) < 30)       __builtin_amdgcn_s_waitcnt(0x0f76);  /* vmcnt(6) */          \
        else if ((kt) == 30) __builtin_amdgcn_s_waitcnt(0x0f74);  /* vmcnt(4) */          \
        if ((kt) < 31) __syncthreads();                                                   \
    }

    bf16x8 bA[4], bB[4];

    // prologue: A tiles 0,1 staged; B tile 0 to regs.  outstanding = A0(2)+A1(2)+B0(4)=8
    ASTAGE(0, 0);
    ASTAGE(1, 1);
    BPREF(bA, 0);
    __builtin_amdgcn_s_waitcnt(0x0f76);  // vmcnt(6): A0 landed for this wave
    __syncthreads();                     // => A0 landed for all waves

    for (int kt = 0; kt < 32; kt += 2) {
        TILE(kt, bA, bB);
        TILE(kt + 1, bB, bA);
    }

#undef TILE
#undef BPREF
#undef ASTAGE

#pragma unroll
    for (int i = 0; i < 8; i++) {
#pragma unroll
        for (int c = 0; c < 4; c++) {
            int col = col0 + wc + c * 16 + lane15;
            float bcol = bias[col];
#pragma unroll
            for (int r = 0; r < 4; r++) {
                int row = row0 + wr + i * 16 + quad * 4 + r;
                Cmat[(size_t)row * 1024 + col] = acc[i][c][r] + bcol;
            }
        }
    }
}

// ---------------- CSR build: histogram of dst ----------------
__global__ void k_hist(const int* __restrict__ ei, int* __restrict__ cnt) {
    int e = blockIdx.x * blockDim.x + threadIdx.x;
    if (e >= N_EDGES) return;
    atomicAdd(&cnt[ei[N_EDGES + e]], 1);
}

// ---------------- CSR build: exclusive prefix scan (single block, 256 thr) ----------------
__global__ void k_scan(const int* __restrict__ cnt, int* __restrict__ offs) {
    __shared__ int wsums[4];
    const int CH = 196;  // 256*196 = 50176 >= 50000
    int t = threadIdx.x;
    int beg = t * CH;
    int end = beg + CH; if (end > N_NODES) end = N_NODES;
    int s = 0;
    for (int i = beg; i < end; i++) s += cnt[i];
    // inclusive wave scan
    int lane = t & 63, w = t >> 6;
    int v = s;
#pragma unroll
    for (int off = 1; off < 64; off <<= 1) {
        int u = __shfl_up(v, off, 64);
        if (lane >= off) v += u;
    }
    if (lane == 63) wsums[w] = v;
    __syncthreads();
    int carry = 0;
    for (int i = 0; i < w; i++) carry += wsums[i];
    int run = carry + v - s;  // exclusive prefix for this thread's chunk
    for (int i = beg; i < end; i++) {
        offs[i] = run;
        run += cnt[i];
    }
    if (t == 255) offs[N_NODES] = run;  // == N_EDGES
}

// ---------------- CSR build: scatter src into dst-sorted order ----------------
__global__ void k_scatter(const int* __restrict__ ei, const int* __restrict__ offs,
                          int* __restrict__ fill, int* __restrict__ ssrc) {
    int e = blockIdx.x * blockDim.x + threadIdx.x;
    if (e >= N_EDGES) return;
    int src = ei[e];
    int dst = ei[N_EDGES + e];
    int pos = offs[dst] + atomicAdd(&fill[dst], 1);
    ssrc[pos] = src;
}

// ---------------- fused attention gather + gelu + gate (one wave per dst node) --------
// Per node: s_e = q[n].k[src_e]/8 per head; softmax without max-subtraction (same as the
// prior verified kernel): agg = (sum ex_e * v[src_e]) / (sum ex_e). h = gelu(agg + skip).
__launch_bounds__(256)
__global__ void k_attn(const int* __restrict__ offs, const int* __restrict__ ssrc,
                       const float* __restrict__ qkvs,
                       const float* __restrict__ gate_w, const float* __restrict__ gate_b,
                       float* __restrict__ out_h, float* __restrict__ exsc) {
    int w = threadIdx.x >> 6, l = threadIdx.x & 63;
    int n = blockIdx.x * 4 + w;
    if (n >= N_NODES) return;

    float4 qv = ((const float4*)(qkvs + (size_t)n * 1024))[l];   // lane l -> dims 4l..4l+3, head = l>>4
    int beg = offs[n], end = offs[n + 1];

    float4 acc = make_float4(0.f, 0.f, 0.f, 0.f);
    float den = 0.f;

    for (int base = beg; base < end; base += 64) {
        int m = end - base; if (m > 64) m = 64;
        int mysrc = (l < m) ? ssrc[base + l] : 0;   // prefetch this chunk's src indices
#pragma unroll 2
        for (int j = 0; j < m; j++) {
            int src = __shfl(mysrc, j, 64);
            const float* row = qkvs + (size_t)src * 1024;
            float4 kv = ((const float4*)(row + 256))[l];
            float4 vv = ((const float4*)(row + 512))[l];
            float p = qv.x * kv.x + qv.y * kv.y + qv.z * kv.z + qv.w * kv.w;
            p += __shfl_xor(p, 1, 16);
            p += __shfl_xor(p, 2, 16);
            p += __shfl_xor(p, 4, 16);
            p += __shfl_xor(p, 8, 16);           // all 16 lanes of a head hold s
            float ex = expf(p * 0.125f);
            den += ex;
            acc.x += ex * vv.x; acc.y += ex * vv.y;
            acc.z += ex * vv.z; acc.w += ex * vv.w;
        }
    }

    float inv = (den > 0.f) ? 1.f / den : 0.f;     // deg-0 node -> agg = 0 (matches ref)
    float4 sk = ((const float4*)(qkvs + (size_t)n * 1024 + 768))[l];  // skip (pure GEMM output)

    float z0 = acc.x * inv + sk.x;
    float z1 = acc.y * inv + sk.y;
    float z2 = acc.z * inv + sk.z;
    float z3 = acc.w * inv + sk.w;

    const float is2 = 0.70710678118f;
    float h0 = 0.5f * z0 * (1.f + erff(z0 * is2));
    float h1 = 0.5f * z1 * (1.f + erff(z1 * is2));
    float h2 = 0.5f * z2 * (1.f + erff(z2 * is2));
    float h3 = 0.5f * z3 * (1.f + erff(z3 * is2));
    ((float4*)(out_h + (size_t)n * 256))[l] = make_float4(h0, h1, h2, h3);

    int d0 = l * 4;
    float s0 = h0 * gate_w[(d0 + 0) * 2] + h1 * gate_w[(d0 + 1) * 2] +
               h2 * gate_w[(d0 + 2) * 2] + h3 * gate_w[(d0 + 3) * 2];
    float s1 = h0 * gate_w[(d0 + 0) * 2 + 1] + h1 * gate_w[(d0 + 1) * 2 + 1] +
               h2 * gate_w[(d0 + 2) * 2 + 1] + h3 * gate_w[(d0 + 3) * 2 + 1];
#pragma unroll
    for (int off = 1; off < 64; off <<= 1) {
        s0 += __shfl_xor(s0, off, 64);
        s1 += __shfl_xor(s1, off, 64);
    }
    if (l == 0) {
        exsc[n * 2 + 0] = expf(s0 + gate_b[0]);
        exsc[n * 2 + 1] = expf(s1 + gate_b[1]);
    }
}

// ---------------- esum[c] = sum_n exsc[n,c] ----------------
__global__ void k_esum(const float* __restrict__ exsc, float* __restrict__ esum) {
    __shared__ float red0[4], red1[4];
    float p0 = 0.f, p1 = 0.f;
    for (int n = blockIdx.x * blockDim.x + threadIdx.x; n < N_NODES; n += gridDim.x * blockDim.x) {
        p0 += exsc[n * 2];
        p1 += exsc[n * 2 + 1];
    }
#pragma unroll
    for (int off = 1; off < 64; off <<= 1) {
        p0 += __shfl_xor(p0, off, 64);
        p1 += __shfl_xor(p1, off, 64);
    }
    int w = threadIdx.x >> 6, l = threadIdx.x & 63;
    if (l == 0) { red0[w] = p0; red1[w] = p1; }
    __syncthreads();
    if (threadIdx.x == 0) {
        atomicAdd(&esum[0], red0[0] + red0[1] + red0[2] + red0[3]);
        atomicAdd(&esum[1], red1[0] + red1[1] + red1[2] + red1[3]);
    }
}

// ---------------- attn/A outputs (fp32) + t[c,d] = sum_n attn[n,c] h[n,d] ----------------
__global__ void k_t(const float* __restrict__ exsc, const float* __restrict__ esum,
                    const float* __restrict__ h_f, const int* __restrict__ label_p,
                    float* __restrict__ attn_out, float* __restrict__ A_out,
                    float* __restrict__ t_ws) {
    int d = threadIdx.x;
    float inv0 = 1.f / esum[0], inv1 = 1.f / esum[1];
    int lab = *label_p;
    int n0 = blockIdx.x * 98;
    int n1 = n0 + 98; if (n1 > N_NODES) n1 = N_NODES;
    float t0 = 0.f, t1 = 0.f;
    for (int n = n0; n < n1; n++) {
        float e0 = exsc[n * 2], e1 = exsc[n * 2 + 1];
        float a0 = e0 * inv0, a1 = e1 * inv1;
        float hv = h_f[(size_t)n * 256 + d];
        t0 += a0 * hv;
        t1 += a1 * hv;
        if (d == 0) attn_out[n * 2] = a0;
        else if (d == 1) attn_out[n * 2 + 1] = a1;
        else if (d == 2) A_out[n] = (lab == 0) ? a0 : a1;
    }
    atomicAdd(&t_ws[d], t0);
    atomicAdd(&t_ws[256 + d], t1);
}

// ---------------- y = t @ pool_w + pool_b (fp32 out) ----------------
__global__ void k_y(const float* __restrict__ t_ws, const float* __restrict__ pool_w,
                    const float* __restrict__ pool_b, float* __restrict__ y_out) {
    int d = threadIdx.x;
    float a0 = pool_b[d], a1 = pool_b[d];
    for (int k = 0; k < 256; k++) {
        float w = pool_w[k * 256 + d];
        a0 += t_ws[k] * w;
        a1 += t_ws[256 + k] * w;
    }
    y_out[d] = a0;
    y_out[256 + d] = a1;
}

extern "C" void kernel_launch(void* const* d_in, const int* in_sizes, int n_in,
                              void* d_out, int out_size, void* d_ws, size_t ws_size,
                              hipStream_t stream) {
    const float* x      = (const float*)d_in[0];
    const int*   ei     = (const int*)d_in[1];
    const int*   label  = (const int*)d_in[2];
    const float* Wq     = (const float*)d_in[3];
    const float* bq     = (const float*)d_in[4];
    const float* Wk     = (const float*)d_in[5];
    const float* bk     = (const float*)d_in[6];
    const float* Wv     = (const float*)d_in[7];
    const float* bv     = (const float*)d_in[8];
    const float* Wskip  = (const float*)d_in[9];
    const float* bskip  = (const float*)d_in[10];
    const float* gate_w = (const float*)d_in[11];
    const float* gate_b = (const float*)d_in[12];
    const float* pool_w = (const float*)d_in[13];
    const float* pool_b = (const float*)d_in[14];

    char* ws = (char*)d_ws;
    size_t off = 0;
    float* qkvs = (float*)(ws + off);                 off += (size_t)M_PAD * 1024 * 4;   // 205.5 MB
    unsigned short* xb = (unsigned short*)(ws + off); off += (size_t)M_PAD * 1024 * 2;   // 102.8 MB
    unsigned short* WT = (unsigned short*)(ws + off); off += (size_t)1024 * 1024 * 2;    // 2 MB
    float* biascat = (float*)(ws + off);              off += 1024 * 4;
    int* cnt  = (int*)(ws + off);                     off += (size_t)N_NODES * 4;        // 200 KB
    int* fill = (int*)(ws + off);                     off += (size_t)N_NODES * 4;        // 200 KB (contig w/ cnt)
    int* offs = (int*)(ws + off);                     off += (size_t)(N_NODES + 1) * 4;
    int* ssrc = (int*)(ws + off);                     off += (size_t)N_EDGES * 4;        // 1.6 MB
    float* exsc = (float*)(ws + off);                 off += (size_t)N_NODES * 2 * 4;    // 0.4 MB
    float* esum = (float*)(ws + off);                 off += 2 * 4;
    float* t_ws = (float*)(ws + off);                 off += 512 * 4;

    // Outputs are FP32, concatenated flat in return order.
    float* out = (float*)d_out;
    float* y_out    = out;                 // 512
    float* attn_out = out + 512;           // 100000
    float* h_out    = out + 100512;        // 12800000
    float* A_out    = out + 12900512;      // 50000

    // zero cnt+fill (contiguous) and esum+t_ws (contiguous)
    hipMemsetAsync(cnt, 0, (size_t)N_NODES * 2 * 4, stream);
    hipMemsetAsync(esum, 0, (2 + 512) * 4, stream);

    k_conv_x<<<4096, 256, 0, stream>>>(x, xb);
    k_build_w<<<4096, 256, 0, stream>>>(Wq, Wk, Wv, Wskip, bq, bk, bv, bskip, WT, biascat);
    k_hist<<<(N_EDGES + 255) / 256, 256, 0, stream>>>(ei, cnt);
    k_scan<<<1, 256, 0, stream>>>(cnt, offs);
    k_scatter<<<(N_EDGES + 255) / 256, 256, 0, stream>>>(ei, offs, fill, ssrc);
    // 196 row-tiles x 4 col-tiles = 784 blocks (784 = 8 XCD * 98, bijective swizzle)
    k_gemm<<<784, 512, 0, stream>>>(xb, WT, biascat, qkvs);
    k_attn<<<12500, 256, 0, stream>>>(offs, ssrc, qkvs, gate_w, gate_b, h_out, exsc);
    k_esum<<<128, 256, 0, stream>>>(exsc, esum);
    k_t<<<512, 256, 0, stream>>>(exsc, esum, h_out, label, attn_out, A_out, t_ws);
    k_y<<<1, 256, 0, stream>>>(t_ws, pool_w, pool_b, y_out);
}

// Round 8
// 823.961 us; speedup vs baseline: 1.0521x; 1.0521x over previous
//
#include <hip/hip_runtime.h>
#include <stdint.h>

#define N_NODES 50000
#define N_EDGES 400000
#define M_PAD   50048   // 391 * 128

typedef __attribute__((ext_vector_type(8))) __bf16 bf16x8;
typedef __attribute__((ext_vector_type(4))) float floatx4;

__device__ __forceinline__ unsigned short f2bf(float f) {
    unsigned int u = __float_as_uint(f);
    unsigned int r = (u + 0x7fffu + ((u >> 16) & 1u)) >> 16;
    return (unsigned short)r;
}

__device__ __forceinline__ void gload_lds16(const void* g, void* l) {
    __builtin_amdgcn_global_load_lds((__attribute__((address_space(1))) void*)g,
                                     (__attribute__((address_space(3))) void*)l,
                                     16, 0, 0);
}

// ---------------- x fp32 -> bf16 (padded to M_PAD rows) ----------------
__global__ void k_conv_x(const float* __restrict__ x, unsigned short* __restrict__ xb) {
    const int total = M_PAD * 256;  // float4 units per row
    for (int u = blockIdx.x * blockDim.x + threadIdx.x; u < total; u += gridDim.x * blockDim.x) {
        int row = u >> 8;
        int c4  = u & 255;
        float4 v = make_float4(0.f, 0.f, 0.f, 0.f);
        if (row < N_NODES) v = ((const float4*)x)[(size_t)row * 256 + c4];
        ushort4 o;
        o.x = f2bf(v.x); o.y = f2bf(v.y); o.z = f2bf(v.z); o.w = f2bf(v.w);
        ((ushort4*)xb)[u] = o;
    }
}

// ---------------- build W^T (bf16, [ncol=1024][k=1024]) + bias concat ----------------
__global__ void k_build_w(const float* __restrict__ Wq, const float* __restrict__ Wk,
                          const float* __restrict__ Wv, const float* __restrict__ Ws,
                          const float* __restrict__ bq, const float* __restrict__ bk,
                          const float* __restrict__ bv, const float* __restrict__ bs,
                          unsigned short* __restrict__ WT, float* __restrict__ biascat) {
    int idx = blockIdx.x * blockDim.x + threadIdx.x;
    if (idx < 1024 * 1024) {
        int n = idx >> 10;        // output col 0..1023
        int k = idx & 1023;       // input dim
        int g = n >> 8, d = n & 255;
        const float* W = (g == 0) ? Wq : (g == 1) ? Wk : (g == 2) ? Wv : Ws;
        WT[idx] = f2bf(W[k * 256 + d]);
    }
    if (idx < 1024) {
        int g = idx >> 8, d = idx & 255;
        const float* B = (g == 0) ? bq : (g == 1) ? bk : (g == 2) ? bv : bs;
        biascat[idx] = B[d];
    }
}

// ---------------- bf16 MFMA GEMM: C[M_PAD][1024] = A[M_PAD][1024] * B[1024][1024] + bias --------
// Round-2 proven 2-phase body (single-buffer LDS, 184us) + XCD-chunked 1-D grid so the
// 8 column-tiles of each A-strip run consecutively on ONE XCD (A-strip 256KB + B 2MB
// stay L2-resident; FETCH ~90MB verified in rounds 3/5). No dbuf (round-3 regression),
// no 256-tile (round-5 occupancy collapse).
__launch_bounds__(256)
__global__ void k_gemm(const unsigned short* __restrict__ A,
                       const unsigned short* __restrict__ BT,
                       const float* __restrict__ bias,
                       float* __restrict__ Cmat) {
    __shared__ unsigned short As[128 * 32];
    __shared__ unsigned short Bs[128 * 32];

    // ---- XCD swizzle: wg -> (row strip yt, col tile xt); 3136 = 8 xcd * 392 ----
    int wg   = blockIdx.x;
    int xcd  = wg & 7;
    int j    = wg >> 3;             // 0..391
    int xt   = j & 7;
    int ygrp = j >> 3;              // 0..48
    int yt   = ygrp * 8 + xcd;
    if (yt >= 391) return;          // uniform early-exit (before any barrier)

    const int row0 = yt * 128;
    const int col0 = xt * 128;

    const int t = threadIdx.x;
    const int w = t >> 6;
    const int l = t & 63;

    const int lr = l >> 2;          // row within 16-row wave chunk
    const int lc = (l & 3) * 8;     // bf16-elem offset within row (16B granules)

    const int wr = (w >> 1) * 64;
    const int wc = (w & 1) * 64;
    const int lane15 = l & 15;
    const int quad = l >> 4;

    floatx4 acc[4][4];
#pragma unroll
    for (int i = 0; i < 4; i++)
#pragma unroll
        for (int j2 = 0; j2 < 4; j2++) acc[i][j2] = (floatx4)0.f;

    for (int kk = 0; kk < 1024; kk += 32) {
        __syncthreads();
#pragma unroll
        for (int issue = 0; issue < 2; issue++) {
            int arow = row0 + issue * 64 + w * 16 + lr;
            gload_lds16(A + (size_t)arow * 1024 + kk + lc, As + issue * 2048 + w * 512);
            int brow = col0 + issue * 64 + w * 16 + lr;
            gload_lds16(BT + (size_t)brow * 1024 + kk + lc, Bs + issue * 2048 + w * 512);
        }
        __builtin_amdgcn_s_waitcnt(0x0f70);  // vmcnt(0)
        __syncthreads();

        bf16x8 af[4], bfr[4];
#pragma unroll
        for (int i = 0; i < 4; i++) {
            af[i]  = *(const bf16x8*)(As + (wr + i * 16 + lane15) * 32 + quad * 8);
            bfr[i] = *(const bf16x8*)(Bs + (wc + i * 16 + lane15) * 32 + quad * 8);
        }
#pragma unroll
        for (int i = 0; i < 4; i++)
#pragma unroll
            for (int j2 = 0; j2 < 4; j2++)
                acc[i][j2] = __builtin_amdgcn_mfma_f32_16x16x32_bf16(af[i], bfr[j2], acc[i][j2], 0, 0, 0);
    }

#pragma unroll
    for (int i = 0; i < 4; i++) {
#pragma unroll
        for (int j2 = 0; j2 < 4; j2++) {
            int col = col0 + wc + j2 * 16 + lane15;
            float bcol = bias[col];
#pragma unroll
            for (int r = 0; r < 4; r++) {
                int row = row0 + wr + i * 16 + quad * 4 + r;
                Cmat[(size_t)row * 1024 + col] = acc[i][j2][r] + bcol;
            }
        }
    }
}

// ---------------- CSR build: histogram of dst ----------------
__global__ void k_hist(const int* __restrict__ ei, int* __restrict__ cnt) {
    int e = blockIdx.x * blockDim.x + threadIdx.x;
    if (e >= N_EDGES) return;
    atomicAdd(&cnt[ei[N_EDGES + e]], 1);
}

// ---------------- CSR build: exclusive prefix scan (single block, 256 thr) ----------------
__global__ void k_scan(const int* __restrict__ cnt, int* __restrict__ offs) {
    __shared__ int wsums[4];
    const int CH = 196;  // 256*196 = 50176 >= 50000
    int t = threadIdx.x;
    int beg = t * CH;
    int end = beg + CH; if (end > N_NODES) end = N_NODES;
    int s = 0;
    for (int i = beg; i < end; i++) s += cnt[i];
    // inclusive wave scan
    int lane = t & 63, w = t >> 6;
    int v = s;
#pragma unroll
    for (int off = 1; off < 64; off <<= 1) {
        int u = __shfl_up(v, off, 64);
        if (lane >= off) v += u;
    }
    if (lane == 63) wsums[w] = v;
    __syncthreads();
    int carry = 0;
    for (int i = 0; i < w; i++) carry += wsums[i];
    int run = carry + v - s;  // exclusive prefix for this thread's chunk
    for (int i = beg; i < end; i++) {
        offs[i] = run;
        run += cnt[i];
    }
    if (t == 255) offs[N_NODES] = run;  // == N_EDGES
}

// ---------------- CSR build: scatter src into dst-sorted order ----------------
__global__ void k_scatter(const int* __restrict__ ei, const int* __restrict__ offs,
                          int* __restrict__ fill, int* __restrict__ ssrc) {
    int e = blockIdx.x * blockDim.x + threadIdx.x;
    if (e >= N_EDGES) return;
    int src = ei[e];
    int dst = ei[N_EDGES + e];
    int pos = offs[dst] + atomicAdd(&fill[dst], 1);
    ssrc[pos] = src;
}

// ---------------- fused attention gather + gelu + gate (one wave per dst node) --------
// Per node: s_e = q[n].k[src_e]/8 per head; softmax without max-subtraction (same as the
// prior verified kernel): agg = (sum ex_e * v[src_e]) / (sum ex_e). h = gelu(agg + skip).
__launch_bounds__(256)
__global__ void k_attn(const int* __restrict__ offs, const int* __restrict__ ssrc,
                       const float* __restrict__ qkvs,
                       const float* __restrict__ gate_w, const float* __restrict__ gate_b,
                       float* __restrict__ out_h, float* __restrict__ exsc) {
    int w = threadIdx.x >> 6, l = threadIdx.x & 63;
    int n = blockIdx.x * 4 + w;
    if (n >= N_NODES) return;

    float4 qv = ((const float4*)(qkvs + (size_t)n * 1024))[l];   // lane l -> dims 4l..4l+3, head = l>>4
    int beg = offs[n], end = offs[n + 1];

    float4 acc = make_float4(0.f, 0.f, 0.f, 0.f);
    float den = 0.f;

    for (int base = beg; base < end; base += 64) {
        int m = end - base; if (m > 64) m = 64;
        int mysrc = (l < m) ? ssrc[base + l] : 0;   // prefetch this chunk's src indices
#pragma unroll 2
        for (int j = 0; j < m; j++) {
            int src = __shfl(mysrc, j, 64);
            const float* row = qkvs + (size_t)src * 1024;
            float4 kv = ((const float4*)(row + 256))[l];
            float4 vv = ((const float4*)(row + 512))[l];
            float p = qv.x * kv.x + qv.y * kv.y + qv.z * kv.z + qv.w * kv.w;
            p += __shfl_xor(p, 1, 16);
            p += __shfl_xor(p, 2, 16);
            p += __shfl_xor(p, 4, 16);
            p += __shfl_xor(p, 8, 16);           // all 16 lanes of a head hold s
            float ex = expf(p * 0.125f);
            den += ex;
            acc.x += ex * vv.x; acc.y += ex * vv.y;
            acc.z += ex * vv.z; acc.w += ex * vv.w;
        }
    }

    float inv = (den > 0.f) ? 1.f / den : 0.f;     // deg-0 node -> agg = 0 (matches ref)
    float4 sk = ((const float4*)(qkvs + (size_t)n * 1024 + 768))[l];  // skip (pure GEMM output)

    float z0 = acc.x * inv + sk.x;
    float z1 = acc.y * inv + sk.y;
    float z2 = acc.z * inv + sk.z;
    float z3 = acc.w * inv + sk.w;

    const float is2 = 0.70710678118f;
    float h0 = 0.5f * z0 * (1.f + erff(z0 * is2));
    float h1 = 0.5f * z1 * (1.f + erff(z1 * is2));
    float h2 = 0.5f * z2 * (1.f + erff(z2 * is2));
    float h3 = 0.5f * z3 * (1.f + erff(z3 * is2));
    ((float4*)(out_h + (size_t)n * 256))[l] = make_float4(h0, h1, h2, h3);

    int d0 = l * 4;
    float s0 = h0 * gate_w[(d0 + 0) * 2] + h1 * gate_w[(d0 + 1) * 2] +
               h2 * gate_w[(d0 + 2) * 2] + h3 * gate_w[(d0 + 3) * 2];
    float s1 = h0 * gate_w[(d0 + 0) * 2 + 1] + h1 * gate_w[(d0 + 1) * 2 + 1] +
               h2 * gate_w[(d0 + 2) * 2 + 1] + h3 * gate_w[(d0 + 3) * 2 + 1];
#pragma unroll
    for (int off = 1; off < 64; off <<= 1) {
        s0 += __shfl_xor(s0, off, 64);
        s1 += __shfl_xor(s1, off, 64);
    }
    if (l == 0) {
        exsc[n * 2 + 0] = expf(s0 + gate_b[0]);
        exsc[n * 2 + 1] = expf(s1 + gate_b[1]);
    }
}

// ---------------- esum[c] = sum_n exsc[n,c] ----------------
__global__ void k_esum(const float* __restrict__ exsc, float* __restrict__ esum) {
    __shared__ float red0[4], red1[4];
    float p0 = 0.f, p1 = 0.f;
    for (int n = blockIdx.x * blockDim.x + threadIdx.x; n < N_NODES; n += gridDim.x * blockDim.x) {
        p0 += exsc[n * 2];
        p1 += exsc[n * 2 + 1];
    }
#pragma unroll
    for (int off = 1; off < 64; off <<= 1) {
        p0 += __shfl_xor(p0, off, 64);
        p1 += __shfl_xor(p1, off, 64);
    }
    int w = threadIdx.x >> 6, l = threadIdx.x & 63;
    if (l == 0) { red0[w] = p0; red1[w] = p1; }
    __syncthreads();
    if (threadIdx.x == 0) {
        atomicAdd(&esum[0], red0[0] + red0[1] + red0[2] + red0[3]);
        atomicAdd(&esum[1], red1[0] + red1[1] + red1[2] + red1[3]);
    }
}

// ---------------- attn/A outputs (fp32) + t[c,d] = sum_n attn[n,c] h[n,d] ----------------
__global__ void k_t(const float* __restrict__ exsc, const float* __restrict__ esum,
                    const float* __restrict__ h_f, const int* __restrict__ label_p,
                    float* __restrict__ attn_out, float* __restrict__ A_out,
                    float* __restrict__ t_ws) {
    int d = threadIdx.x;
    float inv0 = 1.f / esum[0], inv1 = 1.f / esum[1];
    int lab = *label_p;
    int n0 = blockIdx.x * 98;
    int n1 = n0 + 98; if (n1 > N_NODES) n1 = N_NODES;
    float t0 = 0.f, t1 = 0.f;
    for (int n = n0; n < n1; n++) {
        float e0 = exsc[n * 2], e1 = exsc[n * 2 + 1];
        float a0 = e0 * inv0, a1 = e1 * inv1;
        float hv = h_f[(size_t)n * 256 + d];
        t0 += a0 * hv;
        t1 += a1 * hv;
        if (d == 0) attn_out[n * 2] = a0;
        else if (d == 1) attn_out[n * 2 + 1] = a1;
        else if (d == 2) A_out[n] = (lab == 0) ? a0 : a1;
    }
    atomicAdd(&t_ws[d], t0);
    atomicAdd(&t_ws[256 + d], t1);
}

// ---------------- y = t @ pool_w + pool_b (fp32 out) ----------------
__global__ void k_y(const float* __restrict__ t_ws, const float* __restrict__ pool_w,
                    const float* __restrict__ pool_b, float* __restrict__ y_out) {
    int d = threadIdx.x;
    float a0 = pool_b[d], a1 = pool_b[d];
    for (int k = 0; k < 256; k++) {
        float w = pool_w[k * 256 + d];
        a0 += t_ws[k] * w;
        a1 += t_ws[256 + k] * w;
    }
    y_out[d] = a0;
    y_out[256 + d] = a1;
}

extern "C" void kernel_launch(void* const* d_in, const int* in_sizes, int n_in,
                              void* d_out, int out_size, void* d_ws, size_t ws_size,
                              hipStream_t stream) {
    const float* x      = (const float*)d_in[0];
    const int*   ei     = (const int*)d_in[1];
    const int*   label  = (const int*)d_in[2];
    const float* Wq     = (const float*)d_in[3];
    const float* bq     = (const float*)d_in[4];
    const float* Wk     = (const float*)d_in[5];
    const float* bk     = (const float*)d_in[6];
    const float* Wv     = (const float*)d_in[7];
    const float* bv     = (const float*)d_in[8];
    const float* Wskip  = (const float*)d_in[9];
    const float* bskip  = (const float*)d_in[10];
    const float* gate_w = (const float*)d_in[11];
    const float* gate_b = (const float*)d_in[12];
    const float* pool_w = (const float*)d_in[13];
    const float* pool_b = (const float*)d_in[14];

    char* ws = (char*)d_ws;
    size_t off = 0;
    float* qkvs = (float*)(ws + off);                 off += (size_t)M_PAD * 1024 * 4;   // 205.0 MB
    unsigned short* xb = (unsigned short*)(ws + off); off += (size_t)M_PAD * 1024 * 2;   // 102.5 MB
    unsigned short* WT = (unsigned short*)(ws + off); off += (size_t)1024 * 1024 * 2;    // 2 MB
    float* biascat = (float*)(ws + off);              off += 1024 * 4;
    int* cnt  = (int*)(ws + off);                     off += (size_t)N_NODES * 4;        // 200 KB
    int* fill = (int*)(ws + off);                     off += (size_t)N_NODES * 4;        // 200 KB (contig w/ cnt)
    int* offs = (int*)(ws + off);                     off += (size_t)(N_NODES + 1) * 4;
    int* ssrc = (int*)(ws + off);                     off += (size_t)N_EDGES * 4;        // 1.6 MB
    float* exsc = (float*)(ws + off);                 off += (size_t)N_NODES * 2 * 4;    // 0.4 MB
    float* esum = (float*)(ws + off);                 off += 2 * 4;
    float* t_ws = (float*)(ws + off);                 off += 512 * 4;

    // Outputs are FP32, concatenated flat in return order.
    float* out = (float*)d_out;
    float* y_out    = out;                 // 512
    float* attn_out = out + 512;           // 100000
    float* h_out    = out + 100512;        // 12800000
    float* A_out    = out + 12900512;      // 50000

    // zero cnt+fill (contiguous) and esum+t_ws (contiguous)
    hipMemsetAsync(cnt, 0, (size_t)N_NODES * 2 * 4, stream);
    hipMemsetAsync(esum, 0, (2 + 512) * 4, stream);

    k_conv_x<<<4096, 256, 0, stream>>>(x, xb);
    k_build_w<<<4096, 256, 0, stream>>>(Wq, Wk, Wv, Wskip, bq, bk, bv, bskip, WT, biascat);
    k_hist<<<(N_EDGES + 255) / 256, 256, 0, stream>>>(ei, cnt);
    k_scan<<<1, 256, 0, stream>>>(cnt, offs);
    k_scatter<<<(N_EDGES + 255) / 256, 256, 0, stream>>>(ei, offs, fill, ssrc);
    // 8 xcd * 392 j = 3136 blocks; 8 tail blocks idle (yt guard)
    k_gemm<<<3136, 256, 0, stream>>>(xb, WT, biascat, qkvs);
    k_attn<<<12500, 256, 0, stream>>>(offs, ssrc, qkvs, gate_w, gate_b, h_out, exsc);
    k_esum<<<128, 256, 0, stream>>>(exsc, esum);
    k_t<<<512, 256, 0, stream>>>(exsc, esum, h_out, label, attn_out, A_out, t_ws);
    k_y<<<1, 256, 0, stream>>>(t_ws, pool_w, pool_b, y_out);
}